// Round 1
// baseline (7726.251 us; speedup 1.0000x reference)
//
#include <hip/hip_runtime.h>

// Seq2Seq attention-LSTM decoder, B=32, T_ENC=512, H=E=ENC_H=512, V=32000, STEPS=64.
// Strategy: sequential recurrence with small per-step kernels; all logits work
// batched into one (2048x512)@(512x32000) fp32 GEMM at the end (no feedback of
// preds into the recurrence). Requires ~32 MB of d_ws.

#define NEGF (-3.4028235e38f)

static __device__ __forceinline__ float sigf(float x) { return 1.0f / (1.0f + expf(-x)); }

// dst[c*rows + r] = src[r*ld + coff + c]   (rows, cols multiples of 32)
__global__ __launch_bounds__(256) void k_transpose(const float* __restrict__ src,
    float* __restrict__ dst, int rows, int cols, int ld, int coff)
{
    __shared__ float tile[32][33];
    int c0 = blockIdx.x * 32, r0 = blockIdx.y * 32;
    int tx = threadIdx.x & 31, ty = threadIdx.x >> 5;
#pragma unroll
    for (int i = 0; i < 32; i += 8)
        tile[ty + i][tx] = src[(size_t)(r0 + ty + i) * ld + coff + c0 + tx];
    __syncthreads();
#pragma unroll
    for (int i = 0; i < 32; i += 8)
        dst[(size_t)(c0 + ty + i) * rows + r0 + tx] = tile[tx][ty + i];
}

// dst[b,j] = dot(vec[b,:], W[j,:])   (W row-major 512x512)
__global__ __launch_bounds__(512) void k_init_state(const float* __restrict__ vec,
    const float* __restrict__ W, float* __restrict__ dst)
{
    int b = blockIdx.x, j = threadIdx.x;
    __shared__ float sv[512];
    sv[j] = vec[b * 512 + j];
    __syncthreads();
    const float* wr = W + (size_t)j * 512;
    float a0 = 0, a1 = 0, a2 = 0, a3 = 0;
#pragma unroll 4
    for (int k = 0; k < 512; k += 4) {
        float4 w = *reinterpret_cast<const float4*>(wr + k);
        a0 += sv[k] * w.x; a1 += sv[k + 1] * w.y;
        a2 += sv[k + 2] * w.z; a3 += sv[k + 3] * w.w;
    }
    dst[b * 512 + j] = (a0 + a1) + (a2 + a3);
}

// emb_seq[m=t*32+b, :] = (t==0) ? 0 : embedding[trg[b, t-1], :]
__global__ __launch_bounds__(256) void k_gather(const int* __restrict__ trg,
    const float* __restrict__ emb, float* __restrict__ eseq)
{
    int gid = blockIdx.x * 256 + threadIdx.x;  // 2048*128 float4 groups
    int m = gid >> 7, e4 = gid & 127;
    int t = m >> 5, b = m & 31;
    float4 v = make_float4(0.f, 0.f, 0.f, 0.f);
    if (t > 0) {
        int row = trg[b * 64 + (t - 1)];
        v = *reinterpret_cast<const float4*>(emb + (size_t)row * 512 + e4 * 4);
    }
    *reinterpret_cast<float4*>(eseq + (size_t)m * 512 + e4 * 4) = v;
}

// C[M,N] = A[M,K] * B[N,K]^T (+bias). 128x128 tile, BK=32, 256 thr, 8x8 micro.
// All dims divisible by tile sizes in every call. REMAP permutes output rows
// m=t*32+b -> b*64+t (writes logits directly in (B,STEPS,V) layout).
template <int REMAP>
__global__ __launch_bounds__(256) void k_gemm_nt(const float* __restrict__ A, int lda,
    const float* __restrict__ B, int ldb, const float* __restrict__ bias,
    float* __restrict__ C, int N, int K)
{
    __shared__ float sA[32][132];
    __shared__ float sB[32][132];
    int tid = threadIdx.x;
    int n0 = blockIdx.x * 128, m0 = blockIdx.y * 128;
    int tx = tid & 15, ty = tid >> 4;
    float acc[8][8] = {};
    for (int k0 = 0; k0 < K; k0 += 32) {
#pragma unroll
        for (int i = 0; i < 4; ++i) {
            int f4 = tid + i * 256;
            int r = f4 >> 3, c4 = f4 & 7;
            float4 va = *reinterpret_cast<const float4*>(A + (size_t)(m0 + r) * lda + k0 + c4 * 4);
            sA[c4 * 4 + 0][r] = va.x; sA[c4 * 4 + 1][r] = va.y;
            sA[c4 * 4 + 2][r] = va.z; sA[c4 * 4 + 3][r] = va.w;
            float4 vb = *reinterpret_cast<const float4*>(B + (size_t)(n0 + r) * ldb + k0 + c4 * 4);
            sB[c4 * 4 + 0][r] = vb.x; sB[c4 * 4 + 1][r] = vb.y;
            sB[c4 * 4 + 2][r] = vb.z; sB[c4 * 4 + 3][r] = vb.w;
        }
        __syncthreads();
#pragma unroll 8
        for (int k = 0; k < 32; ++k) {
            float a[8], b[8];
            *reinterpret_cast<float4*>(&a[0]) = *reinterpret_cast<const float4*>(&sA[k][ty * 8]);
            *reinterpret_cast<float4*>(&a[4]) = *reinterpret_cast<const float4*>(&sA[k][ty * 8 + 4]);
            *reinterpret_cast<float4*>(&b[0]) = *reinterpret_cast<const float4*>(&sB[k][tx * 8]);
            *reinterpret_cast<float4*>(&b[4]) = *reinterpret_cast<const float4*>(&sB[k][tx * 8 + 4]);
#pragma unroll
            for (int i = 0; i < 8; ++i)
#pragma unroll
                for (int j = 0; j < 8; ++j)
                    acc[i][j] += a[i] * b[j];
        }
        __syncthreads();
    }
#pragma unroll
    for (int i = 0; i < 8; ++i) {
        int row = m0 + ty * 8 + i;
        size_t crow = REMAP ? (size_t)((row & 31) * 64 + (row >> 5)) : (size_t)row;
        float* cp = C + crow * (size_t)N + n0 + tx * 8;
        float v[8];
#pragma unroll
        for (int j = 0; j < 8; ++j) v[j] = acc[i][j];
        if (bias) {
            const float* bb = bias + n0 + tx * 8;
#pragma unroll
            for (int j = 0; j < 8; ++j) v[j] += bb[j];
        }
        *reinterpret_cast<float4*>(cp) = make_float4(v[0], v[1], v[2], v[3]);
        *reinterpret_cast<float4*>(cp + 4) = make_float4(v[4], v[5], v[6], v[7]);
    }
}

// z[b,j] = zemb[b,j] + ba[j] + dot(h[b,:], WaT[:,j])
__global__ __launch_bounds__(128) void k_z(const float* __restrict__ h,
    const float* __restrict__ zemb, const float* __restrict__ WaT,
    const float* __restrict__ ba, float* __restrict__ z)
{
    int b = blockIdx.x, tid = threadIdx.x;
    int j = blockIdx.y * 128 + tid;
    __shared__ float sh[512];
#pragma unroll
    for (int q = 0; q < 4; ++q) sh[tid + q * 128] = h[b * 512 + tid + q * 128];
    __syncthreads();
    float a0 = 0, a1 = 0, a2 = 0, a3 = 0;
#pragma unroll 4
    for (int k = 0; k < 512; k += 4) {
        a0 += sh[k]     * WaT[(size_t)(k) * 512 + j];
        a1 += sh[k + 1] * WaT[(size_t)(k + 1) * 512 + j];
        a2 += sh[k + 2] * WaT[(size_t)(k + 2) * 512 + j];
        a3 += sh[k + 3] * WaT[(size_t)(k + 3) * 512 + j];
    }
    z[b * 512 + j] = zemb[b * 512 + j] + ba[j] + (a0 + a1) + (a2 + a3);
}

// softmax(z[b,:]) (recomputed per e-chunk block), then ctx[b,e] = sum_t aw*enc
__global__ __launch_bounds__(128) void k_softctx(const float* __restrict__ z,
    const float* __restrict__ enc, float* __restrict__ ctx)
{
    int b = blockIdx.x, tid = threadIdx.x;
    __shared__ float p[512];
    __shared__ float red[128];
    float lm = NEGF;
#pragma unroll
    for (int q = 0; q < 4; ++q) {
        float v = z[b * 512 + tid + q * 128];
        p[tid + q * 128] = v;
        lm = fmaxf(lm, v);
    }
    red[tid] = lm;
    __syncthreads();
#pragma unroll
    for (int s = 64; s > 0; s >>= 1) {
        if (tid < s) red[tid] = fmaxf(red[tid], red[tid + s]);
        __syncthreads();
    }
    float mx = red[0];
    __syncthreads();
    float ls = 0;
#pragma unroll
    for (int q = 0; q < 4; ++q) {
        float e = expf(p[tid + q * 128] - mx);
        p[tid + q * 128] = e;
        ls += e;
    }
    red[tid] = ls;
    __syncthreads();
#pragma unroll
    for (int s = 64; s > 0; s >>= 1) {
        if (tid < s) red[tid] += red[tid + s];
        __syncthreads();
    }
    float inv = 1.0f / red[0];
    int e = blockIdx.y * 128 + tid;
    const float* ep = enc + (size_t)b * 512 * 512 + e;
    float a0 = 0, a1 = 0, a2 = 0, a3 = 0;
#pragma unroll 4
    for (int t = 0; t < 512; t += 4) {
        a0 += p[t]     * ep[(size_t)(t) * 512];
        a1 += p[t + 1] * ep[(size_t)(t + 1) * 512];
        a2 += p[t + 2] * ep[(size_t)(t + 2) * 512];
        a3 += p[t + 3] * ep[(size_t)(t + 3) * 512];
    }
    ctx[b * 512 + e] = ((a0 + a1) + (a2 + a3)) * inv;
}

// comb[b,i] = relu(cemb[b,i] + bc[i] + dot(ctx[b,:], WcT[:,i]))
__global__ __launch_bounds__(128) void k_comb(const float* __restrict__ ctx,
    const float* __restrict__ cemb, const float* __restrict__ WcT,
    const float* __restrict__ bc, float* __restrict__ comb)
{
    int b = blockIdx.x, tid = threadIdx.x;
    int i = blockIdx.y * 128 + tid;
    __shared__ float sc[512];
#pragma unroll
    for (int q = 0; q < 4; ++q) sc[tid + q * 128] = ctx[b * 512 + tid + q * 128];
    __syncthreads();
    float a0 = 0, a1 = 0, a2 = 0, a3 = 0;
#pragma unroll 4
    for (int k = 0; k < 512; k += 4) {
        a0 += sc[k]     * WcT[(size_t)(k) * 512 + i];
        a1 += sc[k + 1] * WcT[(size_t)(k + 1) * 512 + i];
        a2 += sc[k + 2] * WcT[(size_t)(k + 2) * 512 + i];
        a3 += sc[k + 3] * WcT[(size_t)(k + 3) * 512 + i];
    }
    float v = cemb[b * 512 + i] + bc[i] + (a0 + a1) + (a2 + a3);
    comb[b * 512 + i] = fmaxf(v, 0.0f);
}

// gates[b,g] = bih[g]+bhh[g] + dot(comb[b,:],WihT[:,g]) + dot(h[b,:],WhhT[:,g])
__global__ __launch_bounds__(128) void k_gates(const float* __restrict__ comb,
    const float* __restrict__ h, const float* __restrict__ WihT,
    const float* __restrict__ WhhT, const float* __restrict__ bih,
    const float* __restrict__ bhh, float* __restrict__ gates)
{
    int b = blockIdx.x, tid = threadIdx.x;
    int g = blockIdx.y * 128 + tid;
    __shared__ float sc[512];
    __shared__ float sh[512];
#pragma unroll
    for (int q = 0; q < 4; ++q) {
        sc[tid + q * 128] = comb[b * 512 + tid + q * 128];
        sh[tid + q * 128] = h[b * 512 + tid + q * 128];
    }
    __syncthreads();
    float a0 = 0, a1 = 0;
#pragma unroll 2
    for (int k = 0; k < 512; k += 2) {
        a0 += sc[k] * WihT[(size_t)k * 2048 + g] + sh[k] * WhhT[(size_t)k * 2048 + g];
        a1 += sc[k + 1] * WihT[(size_t)(k + 1) * 2048 + g] + sh[k + 1] * WhhT[(size_t)(k + 1) * 2048 + g];
    }
    gates[b * 2048 + g] = bih[g] + bhh[g] + a0 + a1;
}

// LSTM cell; updates h,c in place, writes states[b, t, :] (states_t = out2 + t*512)
__global__ __launch_bounds__(512) void k_lstm(const float* __restrict__ gates,
    float* __restrict__ hbuf, float* __restrict__ cbuf, float* __restrict__ states_t)
{
    int b = blockIdx.x, j = threadIdx.x;
    float gi = gates[b * 2048 + j];
    float gf = gates[b * 2048 + 512 + j];
    float gg = gates[b * 2048 + 1024 + j];
    float go = gates[b * 2048 + 1536 + j];
    float c = cbuf[b * 512 + j];
    float cn = sigf(gf) * c + sigf(gi) * tanhf(gg);
    float hn = sigf(go) * tanhf(cn);
    cbuf[b * 512 + j] = cn;
    hbuf[b * 512 + j] = hn;
    states_t[(size_t)b * (64 * 512) + j] = hn;
}

// per-row (m = t*32+b, stored at out0[b][t][:]): argmax (first-index) + logsumexp
__global__ __launch_bounds__(256) void k_rowstats(const float* __restrict__ out0,
    float* __restrict__ lse, float* __restrict__ preds)
{
    int m = blockIdx.x, tid = threadIdx.x;
    int b = m & 31, t = m >> 5;
    const float* row = out0 + ((size_t)b * 64 + t) * 32000;
    float lm = NEGF; int li = 0;
    for (int i = tid; i < 32000; i += 256) {
        float v = row[i];
        if (v > lm) { lm = v; li = i; }
    }
    __shared__ float rm[256];
    __shared__ int ri[256];
    rm[tid] = lm; ri[tid] = li;
    __syncthreads();
#pragma unroll
    for (int s = 128; s > 0; s >>= 1) {
        if (tid < s) {
            float vo = rm[tid + s]; int io = ri[tid + s];
            if (vo > rm[tid] || (vo == rm[tid] && io < ri[tid])) { rm[tid] = vo; ri[tid] = io; }
        }
        __syncthreads();
    }
    float mx = rm[0]; int idx = ri[0];
    __syncthreads();
    float ls = 0;
    for (int i = tid; i < 32000; i += 256) ls += expf(row[i] - mx);
    rm[tid] = ls;
    __syncthreads();
#pragma unroll
    for (int s = 128; s > 0; s >>= 1) {
        if (tid < s) rm[tid] += rm[tid + s];
        __syncthreads();
    }
    if (tid == 0) {
        lse[m] = mx + logf(rm[0]);
        preds[b * 64 + t] = (float)idx;
    }
}

__global__ __launch_bounds__(256) void k_subls(float* __restrict__ out0,
    const float* __restrict__ lse)
{
    int m = blockIdx.x;
    int b = m & 31, t = m >> 5;
    float s = lse[m];
    float* row = out0 + ((size_t)b * 64 + t) * 32000;
    int i = blockIdx.y * 256 + threadIdx.x;
    row[i] -= s;
}

__global__ __launch_bounds__(64) void k_masks(const float* __restrict__ preds,
    float* __restrict__ masks)
{
    int b = threadIdx.x;
    if (b < 32) {
        float mask = 1.0f;
        for (int t = 0; t < 64; ++t) {
            masks[b * 64 + t] = mask;
            if (preds[b * 64 + t] == 2.0f) mask = 0.0f;
        }
    }
}

extern "C" void kernel_launch(void* const* d_in, const int* in_sizes, int n_in,
                              void* d_out, int out_size, void* d_ws, size_t ws_size,
                              hipStream_t stream)
{
    (void)in_sizes; (void)n_in; (void)out_size; (void)ws_size;
    const float* enc  = (const float*)d_in[0];
    const float* ench = (const float*)d_in[1];
    const float* encc = (const float*)d_in[2];
    const int*   trg  = (const int*)d_in[3];
    const float* emb  = (const float*)d_in[5];
    const float* Wa   = (const float*)d_in[6];
    const float* ba   = (const float*)d_in[7];
    const float* Wc   = (const float*)d_in[8];
    const float* bc   = (const float*)d_in[9];
    const float* Wh0  = (const float*)d_in[10];
    const float* Wc0  = (const float*)d_in[11];
    const float* Wih  = (const float*)d_in[12];
    const float* Whh  = (const float*)d_in[13];
    const float* bih  = (const float*)d_in[14];
    const float* bhh  = (const float*)d_in[15];
    const float* Wp   = (const float*)d_in[16];
    const float* bp   = (const float*)d_in[17];
    const float* Wo   = (const float*)d_in[18];
    const float* bo   = (const float*)d_in[19];

    float* ws = (float*)d_ws;                 // ~32 MB of f32 scratch
    float* WaT   = ws;                        // 512*512
    float* WcT   = ws + 262144;               // 512*512
    float* WihT  = ws + 524288;               // 512*2048
    float* WhhT  = ws + 1572864;              // 512*2048
    float* eseq  = ws + 2621440;              // 2048*512
    float* zemb  = ws + 3670016;              // 2048*512
    float* cemb  = ws + 4718592;              // 2048*512
    float* comb  = ws + 5767168;              // 2048*512
    float* pre   = ws + 6815744;              // 2048*512
    float* hbuf  = ws + 7864320;              // 32*512
    float* cbuf  = ws + 7880704;              // 32*512
    float* zbuf  = ws + 7897088;              // 32*512
    float* ctx   = ws + 7913472;              // 32*512
    float* gates = ws + 7929856;              // 32*2048
    float* lse   = ws + 7995392;              // 2048

    float* out0 = (float*)d_out;              // lps  (32,64,32000)
    float* out1 = out0 + 65536000ull;         // preds (32,64) as float
    float* out2 = out1 + 2048;                // states (32,64,512)
    float* out3 = out2 + 1048576;             // masks (32,64) as float

    // one-time prep
    k_transpose<<<dim3(16, 16), 256, 0, stream>>>(Wa, WaT, 512, 512, 1024, 512);
    k_transpose<<<dim3(16, 16), 256, 0, stream>>>(Wc, WcT, 512, 512, 1024, 512);
    k_transpose<<<dim3(16, 64), 256, 0, stream>>>(Wih, WihT, 2048, 512, 512, 0);
    k_transpose<<<dim3(16, 64), 256, 0, stream>>>(Whh, WhhT, 2048, 512, 512, 0);
    k_init_state<<<32, 512, 0, stream>>>(ench, Wh0, hbuf);
    k_init_state<<<32, 512, 0, stream>>>(encc, Wc0, cbuf);
    k_gather<<<1024, 256, 0, stream>>>(trg, emb, eseq);
    k_gemm_nt<0><<<dim3(4, 16), 256, 0, stream>>>(eseq, 512, Wa, 1024, nullptr, zemb, 512, 512);
    k_gemm_nt<0><<<dim3(4, 16), 256, 0, stream>>>(eseq, 512, Wc, 1024, nullptr, cemb, 512, 512);

    // sequential recurrence
    for (int t = 0; t < 64; ++t) {
        k_z<<<dim3(32, 4), 128, 0, stream>>>(hbuf, zemb + (size_t)t * 32 * 512, WaT, ba, zbuf);
        k_softctx<<<dim3(32, 4), 128, 0, stream>>>(zbuf, enc, ctx);
        k_comb<<<dim3(32, 4), 128, 0, stream>>>(ctx, cemb + (size_t)t * 32 * 512, WcT, bc,
                                                comb + (size_t)t * 32 * 512);
        k_gates<<<dim3(32, 16), 128, 0, stream>>>(comb + (size_t)t * 32 * 512, hbuf,
                                                  WihT, WhhT, bih, bhh, gates);
        k_lstm<<<32, 512, 0, stream>>>(gates, hbuf, cbuf, out2 + (size_t)t * 512);
    }

    // batched output projection + log-softmax + argmax
    k_gemm_nt<0><<<dim3(4, 16), 256, 0, stream>>>(comb, 512, Wp, 512, bp, pre, 512, 512);
    k_gemm_nt<1><<<dim3(250, 16), 256, 0, stream>>>(pre, 512, Wo, 512, bo, out0, 32000, 512);
    k_rowstats<<<2048, 256, 0, stream>>>(out0, lse, out1);
    k_subls<<<dim3(2048, 125), 256, 0, stream>>>(out0, lse);
    k_masks<<<1, 64, 0, stream>>>(out1, out3);
}

// Round 4
// 7617.995 us; speedup vs baseline: 1.0142x; 1.0142x over previous
//
#include <hip/hip_runtime.h>

// Seq2Seq attention-LSTM decoder, B=32, T_ENC=512, H=E=ENC_H=512, V=32000, STEPS=64.
// Round 4: NO grid barriers (round-3 hang = plain-launch co-residency deadlock).
// Recurrence = 64 steps x 2 plain kernel launches:
//   k_stepA (32 blocks, batch-local): z GEMV + softmax + ctx via precomputed
//           encWc[b] = enc[b] @ WcCtx^T + comb (relu), writes comb row + combT.
//   k_stepB (256 blocks, column-local): gates GEMV (2 hidden cols/block, all b)
//           + LSTM; hT ping-pong across steps.
// Logits batched into one (2048x512)@(512x32000) fp32 GEMM after the loop.

#define NEGF (-3.4028235e38f)

static __device__ __forceinline__ float sigf(float x) { return 1.0f / (1.0f + expf(-x)); }

// dst[c*rows + r] = src[r*ld + coff + c]
__global__ __launch_bounds__(256) void k_transpose(const float* __restrict__ src,
    float* __restrict__ dst, int rows, int cols, int ld, int coff)
{
    __shared__ float tile[32][33];
    int c0 = blockIdx.x * 32, r0 = blockIdx.y * 32;
    int tx = threadIdx.x & 31, ty = threadIdx.x >> 5;
#pragma unroll
    for (int i = 0; i < 32; i += 8)
        tile[ty + i][tx] = src[(size_t)(r0 + ty + i) * ld + coff + c0 + tx];
    __syncthreads();
#pragma unroll
    for (int i = 0; i < 32; i += 8)
        dst[(size_t)(c0 + ty + i) * rows + r0 + tx] = tile[tx][ty + i];
}

// dst[b,j] = dot(vec[b,:], W[j,:]); writes row-major (optional) + transposed
__global__ __launch_bounds__(512) void k_init_state(const float* __restrict__ vec,
    const float* __restrict__ W, float* __restrict__ dst, float* __restrict__ dstT)
{
    int b = blockIdx.x, j = threadIdx.x;
    __shared__ float sv[512];
    sv[j] = vec[b * 512 + j];
    __syncthreads();
    const float* wr = W + (size_t)j * 512;
    float a0 = 0, a1 = 0, a2 = 0, a3 = 0;
#pragma unroll 4
    for (int k = 0; k < 512; k += 4) {
        float4 w = *reinterpret_cast<const float4*>(wr + k);
        a0 += sv[k] * w.x; a1 += sv[k + 1] * w.y;
        a2 += sv[k + 2] * w.z; a3 += sv[k + 3] * w.w;
    }
    float v = (a0 + a1) + (a2 + a3);
    if (dst) dst[b * 512 + j] = v;
    dstT[j * 32 + b] = v;
}

// emb_seq[m=t*32+b, :] = (t==0) ? 0 : embedding[trg[b, t-1], :]
__global__ __launch_bounds__(256) void k_gather(const int* __restrict__ trg,
    const float* __restrict__ emb, float* __restrict__ eseq)
{
    int gid = blockIdx.x * 256 + threadIdx.x;
    int m = gid >> 7, e4 = gid & 127;
    int t = m >> 5, b = m & 31;
    float4 v = make_float4(0.f, 0.f, 0.f, 0.f);
    if (t > 0) {
        int row = trg[b * 64 + (t - 1)];
        v = *reinterpret_cast<const float4*>(emb + (size_t)row * 512 + e4 * 4);
    }
    *reinterpret_cast<float4*>(eseq + (size_t)m * 512 + e4 * 4) = v;
}

// C[M,N] = A[M,K] * B[N,K]^T (+bias). 128x128 tile, BK=32, 256 thr, 8x8 micro.
// blockIdx.z batches A and C via strides. REMAP: row m=t*32+b -> b*64+t.
template <int REMAP>
__global__ __launch_bounds__(256) void k_gemm_nt(const float* __restrict__ A, int lda,
    size_t strideA, const float* __restrict__ B, int ldb, const float* __restrict__ bias,
    float* __restrict__ C, size_t strideC, int N, int K)
{
    __shared__ float sA[32][132];
    __shared__ float sB[32][132];
    A += strideA * blockIdx.z;
    C += strideC * blockIdx.z;
    int tid = threadIdx.x;
    int n0 = blockIdx.x * 128, m0 = blockIdx.y * 128;
    int tx = tid & 15, ty = tid >> 4;
    float acc[8][8] = {};
    for (int k0 = 0; k0 < K; k0 += 32) {
#pragma unroll
        for (int i = 0; i < 4; ++i) {
            int f4 = tid + i * 256;
            int r = f4 >> 3, c4 = f4 & 7;
            float4 va = *reinterpret_cast<const float4*>(A + (size_t)(m0 + r) * lda + k0 + c4 * 4);
            sA[c4 * 4 + 0][r] = va.x; sA[c4 * 4 + 1][r] = va.y;
            sA[c4 * 4 + 2][r] = va.z; sA[c4 * 4 + 3][r] = va.w;
            float4 vb = *reinterpret_cast<const float4*>(B + (size_t)(n0 + r) * ldb + k0 + c4 * 4);
            sB[c4 * 4 + 0][r] = vb.x; sB[c4 * 4 + 1][r] = vb.y;
            sB[c4 * 4 + 2][r] = vb.z; sB[c4 * 4 + 3][r] = vb.w;
        }
        __syncthreads();
#pragma unroll 8
        for (int k = 0; k < 32; ++k) {
            float a[8], b[8];
            *reinterpret_cast<float4*>(&a[0]) = *reinterpret_cast<const float4*>(&sA[k][ty * 8]);
            *reinterpret_cast<float4*>(&a[4]) = *reinterpret_cast<const float4*>(&sA[k][ty * 8 + 4]);
            *reinterpret_cast<float4*>(&b[0]) = *reinterpret_cast<const float4*>(&sB[k][tx * 8]);
            *reinterpret_cast<float4*>(&b[4]) = *reinterpret_cast<const float4*>(&sB[k][tx * 8 + 4]);
#pragma unroll
            for (int i = 0; i < 8; ++i)
#pragma unroll
                for (int j = 0; j < 8; ++j)
                    acc[i][j] += a[i] * b[j];
        }
        __syncthreads();
    }
#pragma unroll
    for (int i = 0; i < 8; ++i) {
        int row = m0 + ty * 8 + i;
        size_t crow = REMAP ? (size_t)((row & 31) * 64 + (row >> 5)) : (size_t)row;
        float* cp = C + crow * (size_t)N + n0 + tx * 8;
        float v[8];
#pragma unroll
        for (int j = 0; j < 8; ++j) v[j] = acc[i][j];
        if (bias) {
            const float* bb = bias + n0 + tx * 8;
#pragma unroll
            for (int j = 0; j < 8; ++j) v[j] += bb[j];
        }
        *reinterpret_cast<float4*>(cp) = make_float4(v[0], v[1], v[2], v[3]);
        *reinterpret_cast<float4*>(cp + 4) = make_float4(v[4], v[5], v[6], v[7]);
    }
}

// ---- step A: batch-local. grid 32 (one block per b), 1024 threads ---------
__global__ __launch_bounds__(1024) void k_stepA(
    const float* __restrict__ WaT,     // [512 k][512 j]  (= Wa[j, 512+k])
    const float* __restrict__ zemb_t,  // [32][512] (this step, ba folded)
    const float* __restrict__ cemb_t,  // [32][512] (this step, bc folded)
    const float* __restrict__ encWc,   // [32][512 t][512 j]
    const float* __restrict__ h_g,     // [32][512]
    float* __restrict__ comb_t,        // [32][512] row into comb_g
    float* __restrict__ combT)         // [512][32]
{
    int b = blockIdx.x, tid = threadIdx.x;
    int j = tid & 511, kh = tid >> 9;       // split the k-range in halves
    __shared__ float sh[512];
    __shared__ float zp[2][512];
    __shared__ float p[512];
    __shared__ float red[16];
    __shared__ float red2[16];

    if (tid < 512) sh[tid] = h_g[b * 512 + tid];
    __syncthreads();

    // z partial: zp[kh][j] = sum_{k in half} h[k] * WaT[k][j]
    {
        float acc = 0.f;
        const float* hp = sh + kh * 256;
        const float* wp = WaT + (size_t)(kh * 256) * 512 + j;
#pragma unroll 4
        for (int k = 0; k < 256; ++k) acc += hp[k] * wp[(size_t)k * 512];
        zp[kh][j] = acc;
    }
    __syncthreads();

    // finalize z + softmax over 512 (threads 0..511 own one element)
    float zv = 0.f;
    if (tid < 512) zv = zp[0][tid] + zp[1][tid] + zemb_t[b * 512 + tid];
    float m = (tid < 512) ? zv : NEGF;
#pragma unroll
    for (int o = 32; o > 0; o >>= 1) m = fmaxf(m, __shfl_xor(m, o));
    if ((tid & 63) == 0) red[tid >> 6] = m;
    __syncthreads();
    float mx = red[0];
#pragma unroll
    for (int w = 1; w < 16; ++w) mx = fmaxf(mx, red[w]);
    float e = (tid < 512) ? expf(zv - mx) : 0.f;
    float sm = e;
#pragma unroll
    for (int o = 32; o > 0; o >>= 1) sm += __shfl_xor(sm, o);
    if ((tid & 63) == 0) red2[tid >> 6] = sm;
    __syncthreads();
    float S = 0.f;
#pragma unroll
    for (int w = 0; w < 16; ++w) S += red2[w];
    if (tid < 512) p[tid] = e * (1.0f / S);
    __syncthreads();

    // comb partial: sum over this thread's t-half of p[t]*encWc[b][t][j]
    {
        float acc = 0.f;
        const float* pp = p + kh * 256;
        const float* ep = encWc + ((size_t)b << 18) + (size_t)(kh * 256) * 512 + j;
#pragma unroll 4
        for (int k = 0; k < 256; ++k) acc += pp[k] * ep[(size_t)k * 512];
        zp[kh][j] = acc;   // reuse (all prior reads are behind syncs)
    }
    __syncthreads();
    if (tid < 512) {
        float v = zp[0][tid] + zp[1][tid] + cemb_t[b * 512 + tid];
        v = fmaxf(v, 0.f);
        comb_t[b * 512 + tid] = v;
        combT[tid * 32 + b] = v;
    }
}

// ---- step B: column-local gates + LSTM. grid 256, 512 threads -------------
__global__ __launch_bounds__(512) void k_stepB(
    const float* __restrict__ Wih,    // [2048][512]
    const float* __restrict__ Whh,    // [2048][512]
    const float* __restrict__ bih, const float* __restrict__ bhh,
    const float* __restrict__ combT,  // [512][32]
    const float* __restrict__ hTr,    // [512][32]  h(t-1)
    float* __restrict__ hTw,          // [512][32]  h(t)
    float* __restrict__ cT,           // [512][32]
    float* __restrict__ h_g,          // [32][512]
    float* __restrict__ states,       // [32][64][512]
    int tstep)
{
    __shared__ float sg2[2][2][4][32];
    int tid = threadIdx.x, bid = blockIdx.x;
    {
        int bb = tid & 31, g = (tid >> 5) & 3, hf = (tid >> 7) & 1, j2 = tid >> 8;
        int jg = bid * 2 + j2;
        int grow = g * 512 + jg;
        const float* wi = Wih + (size_t)grow * 512 + hf * 256;
        const float* wh = Whh + (size_t)grow * 512 + hf * 256;
        const float* cb = combT + (size_t)hf * 256 * 32 + bb;
        const float* hb = hTr + (size_t)hf * 256 * 32 + bb;
        float acc = 0.f;
#pragma unroll 4
        for (int k4 = 0; k4 < 64; ++k4) {
            float4 wi4 = *reinterpret_cast<const float4*>(wi + k4 * 4);
            float4 wh4 = *reinterpret_cast<const float4*>(wh + k4 * 4);
            acc += wi4.x * cb[(k4 * 4 + 0) * 32] + wh4.x * hb[(k4 * 4 + 0) * 32];
            acc += wi4.y * cb[(k4 * 4 + 1) * 32] + wh4.y * hb[(k4 * 4 + 1) * 32];
            acc += wi4.z * cb[(k4 * 4 + 2) * 32] + wh4.z * hb[(k4 * 4 + 2) * 32];
            acc += wi4.w * cb[(k4 * 4 + 3) * 32] + wh4.w * hb[(k4 * 4 + 3) * 32];
        }
        sg2[hf][j2][g][bb] = acc;
    }
    __syncthreads();
    if (tid < 64) {
        int bb = tid & 31, j2 = tid >> 5;
        int jg = bid * 2 + j2;
        float gi = sg2[0][j2][0][bb] + sg2[1][j2][0][bb] + bih[jg] + bhh[jg];
        float gf = sg2[0][j2][1][bb] + sg2[1][j2][1][bb] + bih[512 + jg] + bhh[512 + jg];
        float gg = sg2[0][j2][2][bb] + sg2[1][j2][2][bb] + bih[1024 + jg] + bhh[1024 + jg];
        float go = sg2[0][j2][3][bb] + sg2[1][j2][3][bb] + bih[1536 + jg] + bhh[1536 + jg];
        float c = cT[jg * 32 + bb];
        float cn = sigf(gf) * c + sigf(gi) * tanhf(gg);
        float hn = sigf(go) * tanhf(cn);
        cT[jg * 32 + bb] = cn;
        hTw[jg * 32 + bb] = hn;
        h_g[bb * 512 + jg] = hn;
        states[((size_t)bb * 64 + tstep) * 512 + jg] = hn;
    }
}

// per-row argmax (first-index) + logsumexp
__global__ __launch_bounds__(256) void k_rowstats(const float* __restrict__ out0,
    float* __restrict__ lse, float* __restrict__ preds)
{
    int m = blockIdx.x, tid = threadIdx.x;
    int b = m & 31, t = m >> 5;
    const float* row = out0 + ((size_t)b * 64 + t) * 32000;
    float lm = NEGF; int li = 0;
    for (int i = tid; i < 32000; i += 256) {
        float v = row[i];
        if (v > lm) { lm = v; li = i; }
    }
    __shared__ float rm[256];
    __shared__ int ri[256];
    rm[tid] = lm; ri[tid] = li;
    __syncthreads();
#pragma unroll
    for (int s = 128; s > 0; s >>= 1) {
        if (tid < s) {
            float vo = rm[tid + s]; int io = ri[tid + s];
            if (vo > rm[tid] || (vo == rm[tid] && io < ri[tid])) { rm[tid] = vo; ri[tid] = io; }
        }
        __syncthreads();
    }
    float mx = rm[0]; int idx = ri[0];
    __syncthreads();
    float ls = 0;
    for (int i = tid; i < 32000; i += 256) ls += expf(row[i] - mx);
    rm[tid] = ls;
    __syncthreads();
#pragma unroll
    for (int s = 128; s > 0; s >>= 1) {
        if (tid < s) rm[tid] += rm[tid + s];
        __syncthreads();
    }
    if (tid == 0) {
        lse[m] = mx + logf(rm[0]);
        preds[b * 64 + t] = (float)idx;
    }
}

__global__ __launch_bounds__(256) void k_subls(float* __restrict__ out0,
    const float* __restrict__ lse)
{
    int m = blockIdx.x;
    int b = m & 31, t = m >> 5;
    float s = lse[m];
    float* row = out0 + ((size_t)b * 64 + t) * 32000;
    int i = blockIdx.y * 256 + threadIdx.x;
    row[i] -= s;
}

__global__ __launch_bounds__(64) void k_masks(const float* __restrict__ preds,
    float* __restrict__ masks)
{
    int b = threadIdx.x;
    if (b < 32) {
        float mask = 1.0f;
        for (int t = 0; t < 64; ++t) {
            masks[b * 64 + t] = mask;
            if (preds[b * 64 + t] == 2.0f) mask = 0.0f;
        }
    }
}

extern "C" void kernel_launch(void* const* d_in, const int* in_sizes, int n_in,
                              void* d_out, int out_size, void* d_ws, size_t ws_size,
                              hipStream_t stream)
{
    (void)in_sizes; (void)n_in; (void)out_size; (void)ws_size;
    const float* enc  = (const float*)d_in[0];
    const float* ench = (const float*)d_in[1];
    const float* encc = (const float*)d_in[2];
    const int*   trg  = (const int*)d_in[3];
    const float* emb  = (const float*)d_in[5];
    const float* Wa   = (const float*)d_in[6];
    const float* ba   = (const float*)d_in[7];
    const float* Wc   = (const float*)d_in[8];
    const float* bc   = (const float*)d_in[9];
    const float* Wh0  = (const float*)d_in[10];
    const float* Wc0  = (const float*)d_in[11];
    const float* Wih  = (const float*)d_in[12];
    const float* Whh  = (const float*)d_in[13];
    const float* bih  = (const float*)d_in[14];
    const float* bhh  = (const float*)d_in[15];
    const float* Wp   = (const float*)d_in[16];
    const float* bp   = (const float*)d_in[17];
    const float* Wo   = (const float*)d_in[18];
    const float* bo   = (const float*)d_in[19];

    float* ws = (float*)d_ws;                 // ~22.4 MB of f32 scratch
    float* WaT   = ws;                        // 512*512
    float* eseq  = ws + 262144;               // 2048*512
    float* zemb  = ws + 1310720;              // 2048*512
    float* cemb  = ws + 2359296;              // 2048*512
    float* comb  = ws + 3407872;              // 2048*512
    float* pre   = ws + 4456448;              // 2048*512
    float* h_g   = ws + 5505024;              // 32*512
    float* hT0   = ws + 5521408;              // 512*32
    float* hT1   = ws + 5537792;              // 512*32
    float* cT    = ws + 5554176;              // 512*32
    float* combT = ws + 5570560;              // 512*32
    float* lse   = ws + 5586944;              // 2048

    float* out0 = (float*)d_out;              // lps  (32,64,32000)
    float* out1 = out0 + 65536000ull;         // preds (32,64) as float
    float* out2 = out1 + 2048;                // states (32,64,512)
    float* out3 = out2 + 1048576;             // masks (32,64) as float

    // encWc (32 MB) staged in the not-yet-written logits region of d_out
    float* encWcB = out0;

    // ---- prep ----
    k_transpose<<<dim3(16, 16), 256, 0, stream>>>(Wa, WaT, 512, 512, 1024, 512);
    k_init_state<<<32, 512, 0, stream>>>(ench, Wh0, h_g, hT0);
    k_init_state<<<32, 512, 0, stream>>>(encc, Wc0, nullptr, cT);
    k_gather<<<1024, 256, 0, stream>>>(trg, emb, eseq);
    k_gemm_nt<0><<<dim3(4, 16, 1), 256, 0, stream>>>(eseq, 512, 0, Wa, 1024, ba, zemb, 0, 512, 512);
    k_gemm_nt<0><<<dim3(4, 16, 1), 256, 0, stream>>>(eseq, 512, 0, Wc, 1024, bc, cemb, 0, 512, 512);
    k_gemm_nt<0><<<dim3(4, 4, 32), 256, 0, stream>>>(enc, 512, (size_t)262144, Wc + 512, 1024,
                                                     nullptr, encWcB, (size_t)262144, 512, 512);

    // ---- recurrence: 2 plain launches per step, no grid sync --------------
    for (int t = 0; t < 64; ++t) {
        k_stepA<<<32, 1024, 0, stream>>>(WaT, zemb + (size_t)t * 32 * 512,
                                         cemb + (size_t)t * 32 * 512, encWcB, h_g,
                                         comb + (size_t)t * 32 * 512, combT);
        const float* hTr = (t & 1) ? hT1 : hT0;
        float*       hTw = (t & 1) ? hT0 : hT1;
        k_stepB<<<256, 512, 0, stream>>>(Wih, Whh, bih, bhh, combT, hTr, hTw, cT,
                                         h_g, out2, t);
    }

    // ---- batched output projection + log-softmax + argmax ----
    k_gemm_nt<0><<<dim3(4, 16, 1), 256, 0, stream>>>(comb, 512, 0, Wp, 512, bp, pre, 0, 512, 512);
    k_gemm_nt<1><<<dim3(250, 16, 1), 256, 0, stream>>>(pre, 512, 0, Wo, 512, bo, out0, 0, 32000, 512);
    k_rowstats<<<2048, 256, 0, stream>>>(out0, lse, out1);
    k_subls<<<dim3(2048, 125), 256, 0, stream>>>(out0, lse);
    k_masks<<<1, 64, 0, stream>>>(out1, out3);
}

// Round 5
// 6274.268 us; speedup vs baseline: 1.2314x; 1.2142x over previous
//
#include <hip/hip_runtime.h>

// Seq2Seq attention-LSTM decoder, B=32, T_ENC=512, H=E=ENC_H=512, V=32000, STEPS=64.
// Round 5: recurrence fused into ONE cooperative kernel (256 blocks = 32 b x 8
// slices, 512 thr, 3 grid barriers/step, hT ping-pong). Fallback = proven
// 2-launch/step path. Logits = one batched fp32 GEMM (m-major block order for
// L2 reuse of Wo). rowstats+subls fused (row stays L2-resident).

#define NEGF (-3.4028235e38f)

static __device__ __forceinline__ float sigf(float x) { return 1.0f / (1.0f + expf(-x)); }

// ---------------- grid barrier (agent scope, generation counter) ------------
static __device__ __forceinline__ void gridbar(unsigned* bar) {
    __syncthreads();
    if (threadIdx.x == 0) {
        unsigned* ctr = bar;
        unsigned* gen = bar + 32;   // separate cache line
        unsigned g = __hip_atomic_load(gen, __ATOMIC_RELAXED, __HIP_MEMORY_SCOPE_AGENT);
        unsigned a = __hip_atomic_fetch_add(ctr, 1u, __ATOMIC_ACQ_REL, __HIP_MEMORY_SCOPE_AGENT);
        if (a == 255u) {
            __hip_atomic_store(ctr, 0u, __ATOMIC_RELAXED, __HIP_MEMORY_SCOPE_AGENT);
            __hip_atomic_store(gen, g + 1u, __ATOMIC_RELEASE, __HIP_MEMORY_SCOPE_AGENT);
        } else {
            while (__hip_atomic_load(gen, __ATOMIC_ACQUIRE, __HIP_MEMORY_SCOPE_AGENT) == g) {
                __builtin_amdgcn_s_sleep(1);
            }
        }
    }
    __syncthreads();
}

// dst[c*rows + r] = src[r*ld + coff + c]
__global__ __launch_bounds__(256) void k_transpose(const float* __restrict__ src,
    float* __restrict__ dst, int rows, int cols, int ld, int coff)
{
    __shared__ float tile[32][33];
    int c0 = blockIdx.x * 32, r0 = blockIdx.y * 32;
    int tx = threadIdx.x & 31, ty = threadIdx.x >> 5;
#pragma unroll
    for (int i = 0; i < 32; i += 8)
        tile[ty + i][tx] = src[(size_t)(r0 + ty + i) * ld + coff + c0 + tx];
    __syncthreads();
#pragma unroll
    for (int i = 0; i < 32; i += 8)
        dst[(size_t)(c0 + ty + i) * rows + r0 + tx] = tile[tx][ty + i];
}

// dst[b,j] = dot(vec[b,:], W[j,:]); writes row-major (optional) + transposed
__global__ __launch_bounds__(512) void k_init_state(const float* __restrict__ vec,
    const float* __restrict__ W, float* __restrict__ dst, float* __restrict__ dstT)
{
    int b = blockIdx.x, j = threadIdx.x;
    __shared__ float sv[512];
    sv[j] = vec[b * 512 + j];
    __syncthreads();
    const float* wr = W + (size_t)j * 512;
    float a0 = 0, a1 = 0, a2 = 0, a3 = 0;
#pragma unroll 4
    for (int k = 0; k < 512; k += 4) {
        float4 w = *reinterpret_cast<const float4*>(wr + k);
        a0 += sv[k] * w.x; a1 += sv[k + 1] * w.y;
        a2 += sv[k + 2] * w.z; a3 += sv[k + 3] * w.w;
    }
    float v = (a0 + a1) + (a2 + a3);
    if (dst) dst[b * 512 + j] = v;
    dstT[j * 32 + b] = v;
}

// emb_seq[m=t*32+b, :] = (t==0) ? 0 : embedding[trg[b, t-1], :]
__global__ __launch_bounds__(256) void k_gather(const int* __restrict__ trg,
    const float* __restrict__ emb, float* __restrict__ eseq)
{
    int gid = blockIdx.x * 256 + threadIdx.x;
    int m = gid >> 7, e4 = gid & 127;
    int t = m >> 5, b = m & 31;
    float4 v = make_float4(0.f, 0.f, 0.f, 0.f);
    if (t > 0) {
        int row = trg[b * 64 + (t - 1)];
        v = *reinterpret_cast<const float4*>(emb + (size_t)row * 512 + e4 * 4);
    }
    *reinterpret_cast<float4*>(eseq + (size_t)m * 512 + e4 * 4) = v;
}

// C[M,N] = A[M,K] * B[N,K]^T (+bias). 128x128 tile, BK=32, 256 thr, 8x8 micro.
// m-tiles on blockIdx.x (consecutive blocks share the same B tile -> L2 reuse).
// blockIdx.z batches A and C via strides. REMAP: row m=t*32+b -> b*64+t.
template <int REMAP>
__global__ __launch_bounds__(256) void k_gemm_nt(const float* __restrict__ A, int lda,
    size_t strideA, const float* __restrict__ B, int ldb, const float* __restrict__ bias,
    float* __restrict__ C, size_t strideC, int N, int K)
{
    __shared__ float sA[32][132];
    __shared__ float sB[32][132];
    A += strideA * blockIdx.z;
    C += strideC * blockIdx.z;
    int tid = threadIdx.x;
    int m0 = blockIdx.x * 128, n0 = blockIdx.y * 128;
    int tx = tid & 15, ty = tid >> 4;
    float acc[8][8] = {};
    for (int k0 = 0; k0 < K; k0 += 32) {
#pragma unroll
        for (int i = 0; i < 4; ++i) {
            int f4 = tid + i * 256;
            int r = f4 >> 3, c4 = f4 & 7;
            float4 va = *reinterpret_cast<const float4*>(A + (size_t)(m0 + r) * lda + k0 + c4 * 4);
            sA[c4 * 4 + 0][r] = va.x; sA[c4 * 4 + 1][r] = va.y;
            sA[c4 * 4 + 2][r] = va.z; sA[c4 * 4 + 3][r] = va.w;
            float4 vb = *reinterpret_cast<const float4*>(B + (size_t)(n0 + r) * ldb + k0 + c4 * 4);
            sB[c4 * 4 + 0][r] = vb.x; sB[c4 * 4 + 1][r] = vb.y;
            sB[c4 * 4 + 2][r] = vb.z; sB[c4 * 4 + 3][r] = vb.w;
        }
        __syncthreads();
#pragma unroll 8
        for (int k = 0; k < 32; ++k) {
            float a[8], b[8];
            *reinterpret_cast<float4*>(&a[0]) = *reinterpret_cast<const float4*>(&sA[k][ty * 8]);
            *reinterpret_cast<float4*>(&a[4]) = *reinterpret_cast<const float4*>(&sA[k][ty * 8 + 4]);
            *reinterpret_cast<float4*>(&b[0]) = *reinterpret_cast<const float4*>(&sB[k][tx * 8]);
            *reinterpret_cast<float4*>(&b[4]) = *reinterpret_cast<const float4*>(&sB[k][tx * 8 + 4]);
#pragma unroll
            for (int i = 0; i < 8; ++i)
#pragma unroll
                for (int j = 0; j < 8; ++j)
                    acc[i][j] += a[i] * b[j];
        }
        __syncthreads();
    }
#pragma unroll
    for (int i = 0; i < 8; ++i) {
        int row = m0 + ty * 8 + i;
        size_t crow = REMAP ? (size_t)((row & 31) * 64 + (row >> 5)) : (size_t)row;
        float* cp = C + crow * (size_t)N + n0 + tx * 8;
        float v[8];
#pragma unroll
        for (int j = 0; j < 8; ++j) v[j] = acc[i][j];
        if (bias) {
            const float* bb = bias + n0 + tx * 8;
#pragma unroll
            for (int j = 0; j < 8; ++j) v[j] += bb[j];
        }
        *reinterpret_cast<float4*>(cp) = make_float4(v[0], v[1], v[2], v[3]);
        *reinterpret_cast<float4*>(cp + 4) = make_float4(v[4], v[5], v[6], v[7]);
    }
}

// ---------------- fused 64-step decoder (cooperative) ----------------------
// grid 256 = (b = blk>>3, s = blk&7), 512 threads, 133 KB LDS -> 1 block/CU.
__global__ __launch_bounds__(512) void k_fused(
    const float* __restrict__ WaT,    // [512 k][512 j]  (= Wa[j, 512+k])
    const float* __restrict__ zemb,   // [2048][512], ba folded
    const float* __restrict__ cemb,   // [2048][512], bc folded
    const float* __restrict__ encWc,  // [32][512 t][512 j]
    const float* __restrict__ Wih,    // [2048][512]
    const float* __restrict__ Whh,    // [2048][512]
    const float* __restrict__ bih, const float* __restrict__ bhh,
    float* __restrict__ h_g,          // [32][512]
    float* __restrict__ hT0,          // [512][32] ping
    float* __restrict__ hT1,          // [512][32] pong
    float* __restrict__ cT_g,         // [512][32]
    float* __restrict__ z_g,          // [32][512]
    float* __restrict__ combT_g,      // [512][32]
    float* __restrict__ comb_g,       // [2048][512]
    float* __restrict__ states,       // [32][64][512]
    unsigned* __restrict__ bar)
{
    __shared__ float eW[512][64];     // 128 KB, persistent encWc slice
    __shared__ float zl[512];
    __shared__ float red8[8][64];
    __shared__ float wred[8];
    __shared__ float wred2[8];
    __shared__ float sg2[2][2][4][32];

    int tid = threadIdx.x, bid = blockIdx.x;
    int b = bid >> 3, s = bid & 7;
    int jj = tid & 63, q = tid >> 6;

    // persistent load of encWc[b][:, s*64 .. +64)
    {
        const float* src = encWc + ((size_t)b << 18) + s * 64;
        for (int i = tid; i < 512 * 16; i += 512) {
            int t = i >> 4, c4 = i & 15;
            float4 v = *reinterpret_cast<const float4*>(src + (size_t)t * 512 + c4 * 4);
            *reinterpret_cast<float4*>(&eW[t][c4 * 4]) = v;
        }
    }

    for (int tstep = 0; tstep < 64; ++tstep) {
        const float* hTr = (tstep & 1) ? hT1 : hT0;   // h(t-1), transposed
        float*       hTw = (tstep & 1) ? hT0 : hT1;   // h(t)

        // ---- P1: z[b, s*64+jj] = zemb + h . WaT ----
        {
            float acc = 0.f;
            const float* hp = h_g + b * 512 + q * 64;
            const float* wp = WaT + (size_t)(q * 64) * 512 + s * 64 + jj;
#pragma unroll 4
            for (int k = 0; k < 64; ++k)
                acc += hp[k] * wp[(size_t)k * 512];
            __syncthreads();   // red8 was read in P2 of previous step
            red8[q][jj] = acc;
        }
        __syncthreads();
        if (tid < 64) {
            float v = 0.f;
#pragma unroll
            for (int r = 0; r < 8; ++r) v += red8[r][jj];
            v += zemb[((size_t)tstep * 32 + b) * 512 + s * 64 + jj];
            z_g[b * 512 + s * 64 + jj] = v;
        }
        gridbar(bar);

        // ---- P2: softmax(z[b,:]) then comb slice from LDS encWc ----
        {
            float zv = z_g[b * 512 + tid];
            float m = zv;
#pragma unroll
            for (int o = 32; o > 0; o >>= 1) m = fmaxf(m, __shfl_xor(m, o));
            if ((tid & 63) == 0) wred[tid >> 6] = m;
            __syncthreads();
            float mx = fmaxf(fmaxf(fmaxf(wred[0], wred[1]), fmaxf(wred[2], wred[3])),
                             fmaxf(fmaxf(wred[4], wred[5]), fmaxf(wred[6], wred[7])));
            float e = expf(zv - mx);
            zl[tid] = e;
            float sm = e;
#pragma unroll
            for (int o = 32; o > 0; o >>= 1) sm += __shfl_xor(sm, o);
            if ((tid & 63) == 0) wred2[tid >> 6] = sm;
            __syncthreads();
            float ssum = ((wred2[0] + wred2[1]) + (wred2[2] + wred2[3]))
                       + ((wred2[4] + wred2[5]) + (wred2[6] + wred2[7]));
            float inv = 1.0f / ssum;

            float acc = 0.f;
#pragma unroll 4
            for (int t = 0; t < 64; ++t)
                acc += zl[q * 64 + t] * eW[q * 64 + t][jj];
            red8[q][jj] = acc;
            __syncthreads();
            if (tid < 64) {
                float v = 0.f;
#pragma unroll
                for (int r = 0; r < 8; ++r) v += red8[r][jj];
                v = v * inv + cemb[((size_t)tstep * 32 + b) * 512 + s * 64 + jj];
                v = fmaxf(v, 0.f);
                comb_g[((size_t)tstep * 32 + b) * 512 + s * 64 + jj] = v;
                combT_g[(size_t)(s * 64 + jj) * 32 + b] = v;
            }
        }
        gridbar(bar);

        // ---- P3: gates (block owns 2 hidden cols x all b) + LSTM ----
        {
            int bb = tid & 31, g = (tid >> 5) & 3, hf = (tid >> 7) & 1, j2 = tid >> 8;
            int jg = bid * 2 + j2;
            int grow = g * 512 + jg;
            const float* wi = Wih + (size_t)grow * 512 + hf * 256;
            const float* wh = Whh + (size_t)grow * 512 + hf * 256;
            const float* cb = combT_g + (size_t)hf * 256 * 32 + bb;
            const float* hb = hTr + (size_t)hf * 256 * 32 + bb;
            float acc = 0.f;
#pragma unroll 4
            for (int k4 = 0; k4 < 64; ++k4) {
                float4 wi4 = *reinterpret_cast<const float4*>(wi + k4 * 4);
                float4 wh4 = *reinterpret_cast<const float4*>(wh + k4 * 4);
                acc += wi4.x * cb[(k4 * 4 + 0) * 32] + wh4.x * hb[(k4 * 4 + 0) * 32];
                acc += wi4.y * cb[(k4 * 4 + 1) * 32] + wh4.y * hb[(k4 * 4 + 1) * 32];
                acc += wi4.z * cb[(k4 * 4 + 2) * 32] + wh4.z * hb[(k4 * 4 + 2) * 32];
                acc += wi4.w * cb[(k4 * 4 + 3) * 32] + wh4.w * hb[(k4 * 4 + 3) * 32];
            }
            sg2[hf][j2][g][bb] = acc;
        }
        __syncthreads();
        if (tid < 64) {
            int bb = tid & 31, j2 = tid >> 5;
            int jg = bid * 2 + j2;
            float gi = sg2[0][j2][0][bb] + sg2[1][j2][0][bb] + bih[jg] + bhh[jg];
            float gf = sg2[0][j2][1][bb] + sg2[1][j2][1][bb] + bih[512 + jg] + bhh[512 + jg];
            float gg = sg2[0][j2][2][bb] + sg2[1][j2][2][bb] + bih[1024 + jg] + bhh[1024 + jg];
            float go = sg2[0][j2][3][bb] + sg2[1][j2][3][bb] + bih[1536 + jg] + bhh[1536 + jg];
            float c = cT_g[jg * 32 + bb];
            float cn = sigf(gf) * c + sigf(gi) * tanhf(gg);
            float hn = sigf(go) * tanhf(cn);
            cT_g[jg * 32 + bb] = cn;
            hTw[jg * 32 + bb] = hn;
            h_g[bb * 512 + jg] = hn;
            states[((size_t)bb * 64 + tstep) * 512 + jg] = hn;
        }
        gridbar(bar);
    }
}

// ---- fallback step A: batch-local. grid 32, 1024 threads ------------------
__global__ __launch_bounds__(1024) void k_stepA(
    const float* __restrict__ WaT, const float* __restrict__ zemb_t,
    const float* __restrict__ cemb_t, const float* __restrict__ encWc,
    const float* __restrict__ h_g, float* __restrict__ comb_t,
    float* __restrict__ combT)
{
    int b = blockIdx.x, tid = threadIdx.x;
    int j = tid & 511, kh = tid >> 9;
    __shared__ float sh[512];
    __shared__ float zp[2][512];
    __shared__ float p[512];
    __shared__ float red[16];
    __shared__ float red2[16];

    if (tid < 512) sh[tid] = h_g[b * 512 + tid];
    __syncthreads();
    {
        float acc = 0.f;
        const float* hp = sh + kh * 256;
        const float* wp = WaT + (size_t)(kh * 256) * 512 + j;
#pragma unroll 4
        for (int k = 0; k < 256; ++k) acc += hp[k] * wp[(size_t)k * 512];
        zp[kh][j] = acc;
    }
    __syncthreads();
    float zv = 0.f;
    if (tid < 512) zv = zp[0][tid] + zp[1][tid] + zemb_t[b * 512 + tid];
    float m = (tid < 512) ? zv : NEGF;
#pragma unroll
    for (int o = 32; o > 0; o >>= 1) m = fmaxf(m, __shfl_xor(m, o));
    if ((tid & 63) == 0) red[tid >> 6] = m;
    __syncthreads();
    float mx = red[0];
#pragma unroll
    for (int w = 1; w < 16; ++w) mx = fmaxf(mx, red[w]);
    float e = (tid < 512) ? expf(zv - mx) : 0.f;
    float sm = e;
#pragma unroll
    for (int o = 32; o > 0; o >>= 1) sm += __shfl_xor(sm, o);
    if ((tid & 63) == 0) red2[tid >> 6] = sm;
    __syncthreads();
    float S = 0.f;
#pragma unroll
    for (int w = 0; w < 16; ++w) S += red2[w];
    if (tid < 512) p[tid] = e * (1.0f / S);
    __syncthreads();
    {
        float acc = 0.f;
        const float* pp = p + kh * 256;
        const float* ep = encWc + ((size_t)b << 18) + (size_t)(kh * 256) * 512 + j;
#pragma unroll 4
        for (int k = 0; k < 256; ++k) acc += pp[k] * ep[(size_t)k * 512];
        zp[kh][j] = acc;
    }
    __syncthreads();
    if (tid < 512) {
        float v = zp[0][tid] + zp[1][tid] + cemb_t[b * 512 + tid];
        v = fmaxf(v, 0.f);
        comb_t[b * 512 + tid] = v;
        combT[tid * 32 + b] = v;
    }
}

// ---- fallback step B: column-local gates + LSTM. grid 256, 512 threads ----
__global__ __launch_bounds__(512) void k_stepB(
    const float* __restrict__ Wih, const float* __restrict__ Whh,
    const float* __restrict__ bih, const float* __restrict__ bhh,
    const float* __restrict__ combT, const float* __restrict__ hTr,
    float* __restrict__ hTw, float* __restrict__ cT, float* __restrict__ h_g,
    float* __restrict__ states, int tstep)
{
    __shared__ float sg2[2][2][4][32];
    int tid = threadIdx.x, bid = blockIdx.x;
    {
        int bb = tid & 31, g = (tid >> 5) & 3, hf = (tid >> 7) & 1, j2 = tid >> 8;
        int jg = bid * 2 + j2;
        int grow = g * 512 + jg;
        const float* wi = Wih + (size_t)grow * 512 + hf * 256;
        const float* wh = Whh + (size_t)grow * 512 + hf * 256;
        const float* cb = combT + (size_t)hf * 256 * 32 + bb;
        const float* hb = hTr + (size_t)hf * 256 * 32 + bb;
        float acc = 0.f;
#pragma unroll 4
        for (int k4 = 0; k4 < 64; ++k4) {
            float4 wi4 = *reinterpret_cast<const float4*>(wi + k4 * 4);
            float4 wh4 = *reinterpret_cast<const float4*>(wh + k4 * 4);
            acc += wi4.x * cb[(k4 * 4 + 0) * 32] + wh4.x * hb[(k4 * 4 + 0) * 32];
            acc += wi4.y * cb[(k4 * 4 + 1) * 32] + wh4.y * hb[(k4 * 4 + 1) * 32];
            acc += wi4.z * cb[(k4 * 4 + 2) * 32] + wh4.z * hb[(k4 * 4 + 2) * 32];
            acc += wi4.w * cb[(k4 * 4 + 3) * 32] + wh4.w * hb[(k4 * 4 + 3) * 32];
        }
        sg2[hf][j2][g][bb] = acc;
    }
    __syncthreads();
    if (tid < 64) {
        int bb = tid & 31, j2 = tid >> 5;
        int jg = bid * 2 + j2;
        float gi = sg2[0][j2][0][bb] + sg2[1][j2][0][bb] + bih[jg] + bhh[jg];
        float gf = sg2[0][j2][1][bb] + sg2[1][j2][1][bb] + bih[512 + jg] + bhh[512 + jg];
        float gg = sg2[0][j2][2][bb] + sg2[1][j2][2][bb] + bih[1024 + jg] + bhh[1024 + jg];
        float go = sg2[0][j2][3][bb] + sg2[1][j2][3][bb] + bih[1536 + jg] + bhh[1536 + jg];
        float c = cT[jg * 32 + bb];
        float cn = sigf(gf) * c + sigf(gi) * tanhf(gg);
        float hn = sigf(go) * tanhf(cn);
        cT[jg * 32 + bb] = cn;
        hTw[jg * 32 + bb] = hn;
        h_g[bb * 512 + jg] = hn;
        states[((size_t)bb * 64 + tstep) * 512 + jg] = hn;
    }
}

// per-row: argmax (first-index) + logsumexp + in-place log-softmax write
__global__ __launch_bounds__(256) void k_rowfinal(float* __restrict__ out0,
    float* __restrict__ preds)
{
    int m = blockIdx.x, tid = threadIdx.x;
    int b = m & 31, t = m >> 5;
    float* row = out0 + ((size_t)b * 64 + t) * 32000;
    float lm = NEGF; int li = 0;
    for (int i = tid; i < 32000; i += 256) {
        float v = row[i];
        if (v > lm) { lm = v; li = i; }
    }
    __shared__ float rm[256];
    __shared__ int ri[256];
    rm[tid] = lm; ri[tid] = li;
    __syncthreads();
#pragma unroll
    for (int s = 128; s > 0; s >>= 1) {
        if (tid < s) {
            float vo = rm[tid + s]; int io = ri[tid + s];
            if (vo > rm[tid] || (vo == rm[tid] && io < ri[tid])) { rm[tid] = vo; ri[tid] = io; }
        }
        __syncthreads();
    }
    float mx = rm[0]; int idx = ri[0];
    __syncthreads();
    float ls = 0;
    for (int i = tid; i < 32000; i += 256) ls += expf(row[i] - mx);
    rm[tid] = ls;
    __syncthreads();
#pragma unroll
    for (int s = 128; s > 0; s >>= 1) {
        if (tid < s) rm[tid] += rm[tid + s];
        __syncthreads();
    }
    float lse = mx + logf(rm[0]);
    if (tid == 0) preds[b * 64 + t] = (float)idx;
    __syncthreads();
    for (int i = tid; i < 32000; i += 256) row[i] -= lse;
}

__global__ __launch_bounds__(64) void k_masks(const float* __restrict__ preds,
    float* __restrict__ masks)
{
    int b = threadIdx.x;
    if (b < 32) {
        float mask = 1.0f;
        for (int t = 0; t < 64; ++t) {
            masks[b * 64 + t] = mask;
            if (preds[b * 64 + t] == 2.0f) mask = 0.0f;
        }
    }
}

extern "C" void kernel_launch(void* const* d_in, const int* in_sizes, int n_in,
                              void* d_out, int out_size, void* d_ws, size_t ws_size,
                              hipStream_t stream)
{
    (void)in_sizes; (void)n_in; (void)out_size; (void)ws_size;
    const float* enc  = (const float*)d_in[0];
    const float* ench = (const float*)d_in[1];
    const float* encc = (const float*)d_in[2];
    const int*   trg  = (const int*)d_in[3];
    const float* emb  = (const float*)d_in[5];
    const float* Wa   = (const float*)d_in[6];
    const float* ba   = (const float*)d_in[7];
    const float* Wc   = (const float*)d_in[8];
    const float* bc   = (const float*)d_in[9];
    const float* Wh0  = (const float*)d_in[10];
    const float* Wc0  = (const float*)d_in[11];
    const float* Wih  = (const float*)d_in[12];
    const float* Whh  = (const float*)d_in[13];
    const float* bih  = (const float*)d_in[14];
    const float* bhh  = (const float*)d_in[15];
    const float* Wp   = (const float*)d_in[16];
    const float* bp   = (const float*)d_in[17];
    const float* Wo   = (const float*)d_in[18];
    const float* bo   = (const float*)d_in[19];

    float* ws = (float*)d_ws;                 // ~22.5 MB of f32 scratch
    float* WaT   = ws;                        // 512*512
    float* eseq  = ws + 262144;               // 2048*512
    float* zemb  = ws + 1310720;              // 2048*512
    float* cemb  = ws + 2359296;              // 2048*512
    float* comb  = ws + 3407872;              // 2048*512
    float* pre   = ws + 4456448;              // 2048*512
    float* h_g   = ws + 5505024;              // 32*512
    float* hT0   = ws + 5521408;              // 512*32
    float* hT1   = ws + 5537792;              // 512*32
    float* cT    = ws + 5554176;              // 512*32
    float* z_g   = ws + 5570560;              // 32*512
    float* combT = ws + 5586944;              // 512*32
    unsigned* bar = (unsigned*)(ws + 5603328);// 256 B barrier state

    float* out0 = (float*)d_out;              // lps  (32,64,32000)
    float* out1 = out0 + 65536000ull;         // preds (32,64) as float
    float* out2 = out1 + 2048;                // states (32,64,512)
    float* out3 = out2 + 1048576;             // masks (32,64) as float

    // encWc (32 MB) staged in the not-yet-written logits region of d_out
    float* encWcB = out0;

    // ---- prep ----
    k_transpose<<<dim3(16, 16), 256, 0, stream>>>(Wa, WaT, 512, 512, 1024, 512);
    k_init_state<<<32, 512, 0, stream>>>(ench, Wh0, h_g, hT0);
    k_init_state<<<32, 512, 0, stream>>>(encc, Wc0, nullptr, cT);
    k_gather<<<1024, 256, 0, stream>>>(trg, emb, eseq);
    k_gemm_nt<0><<<dim3(16, 4, 1), 256, 0, stream>>>(eseq, 512, 0, Wa, 1024, ba, zemb, 0, 512, 512);
    k_gemm_nt<0><<<dim3(16, 4, 1), 256, 0, stream>>>(eseq, 512, 0, Wc, 1024, bc, cemb, 0, 512, 512);
    k_gemm_nt<0><<<dim3(4, 4, 32), 256, 0, stream>>>(enc, 512, (size_t)262144, Wc + 512, 1024,
                                                     nullptr, encWcB, (size_t)262144, 512, 512);
    hipMemsetAsync(bar, 0, 256, stream);

    // ---- fused recurrence: cooperative launch; fallback = 2-launch/step ----
    {
        const float* a0 = WaT;  const float* a1 = zemb; const float* a2 = cemb;
        const float* a3 = encWcB; const float* a4 = Wih; const float* a5 = Whh;
        const float* a6 = bih;  const float* a7 = bhh;
        float* a8 = h_g;  float* a9 = hT0; float* a10 = hT1; float* a11 = cT;
        float* a12 = z_g; float* a13 = combT; float* a14 = comb; float* a15 = out2;
        unsigned* a16 = bar;
        void* args[] = { &a0,&a1,&a2,&a3,&a4,&a5,&a6,&a7,&a8,&a9,&a10,&a11,
                         &a12,&a13,&a14,&a15,&a16 };
        hipError_t e = hipLaunchCooperativeKernel((const void*)k_fused, dim3(256), dim3(512),
                                                  args, 0, stream);
        if (e != hipSuccess) {
            (void)hipGetLastError();
            for (int t = 0; t < 64; ++t) {
                k_stepA<<<32, 1024, 0, stream>>>(WaT, zemb + (size_t)t * 32 * 512,
                                                 cemb + (size_t)t * 32 * 512, encWcB, h_g,
                                                 comb + (size_t)t * 32 * 512, combT);
                const float* hTr = (t & 1) ? hT1 : hT0;
                float*       hTw = (t & 1) ? hT0 : hT1;
                k_stepB<<<256, 512, 0, stream>>>(Wih, Whh, bih, bhh, combT, hTr, hTw, cT,
                                                 h_g, out2, t);
            }
        }
    }

    // ---- batched output projection + log-softmax + argmax ----
    k_gemm_nt<0><<<dim3(16, 4, 1), 256, 0, stream>>>(comb, 512, 0, Wp, 512, bp, pre, 0, 512, 512);
    k_gemm_nt<1><<<dim3(16, 250, 1), 256, 0, stream>>>(pre, 512, 0, Wo, 512, bo, out0, 0, 32000, 512);
    k_rowfinal<<<2048, 256, 0, stream>>>(out0, out1);
    k_masks<<<1, 64, 0, stream>>>(out1, out3);
}